// Round 7
// baseline (1269.185 us; speedup 1.0000x reference)
//
#include <hip/hip_runtime.h>

typedef unsigned short u16;
typedef unsigned int uint;

using f32x4 = __attribute__((ext_vector_type(4))) float;
using bf16x8 = __attribute__((ext_vector_type(8))) __bf16;
using u32x4 = __attribute__((ext_vector_type(4))) uint;

static __device__ __forceinline__ bf16x8 as_bf16x8(uint4 u) {
    union { uint4 a; bf16x8 b; } c; c.a = u; return c.b;
}
static __device__ __forceinline__ bf16x8 as_bf16x8v(u32x4 u) {
    union { u32x4 a; bf16x8 b; } c; c.a = u; return c.b;
}
static __device__ __forceinline__ float bf2f(u16 h) {
    union { uint u; float f; } c; c.u = ((uint)h) << 16; return c.f;
}
static __device__ __forceinline__ u16 f2bf(float f) {
    union { float f; uint u; } c; c.f = f;
    uint u = c.u;
    return (u16)((u + 0x7fffu + ((u >> 16) & 1u)) >> 16);
}
static __device__ __forceinline__ float fast_sigmoid(float x) {
    x = fminf(30.f, fmaxf(-30.f, x));
    return __builtin_amdgcn_rcpf(1.0f + __builtin_amdgcn_exp2f(x * -1.44269504f));
}
static __device__ __forceinline__ float fast_tanh(float x) {
    x = fminf(15.f, fmaxf(-15.f, x));
    return 1.0f - 2.0f * __builtin_amdgcn_rcpf(1.0f + __builtin_amdgcn_exp2f(x * 2.88539008f));
}

// L1-bypassing 16B load (sc0): reads the XCD-shared L2 directly, so peer-block
// writes (write-through L1 -> L2) are visible WITHOUT agent-scope fences.
static __device__ __forceinline__ u32x4 load_b128_sc0(const u16* p) {
    u32x4 r;
    asm volatile("global_load_dwordx4 %0, %1, off sc0" : "=v"(r) : "v"(p) : "memory");
    return r;
}
static __device__ __forceinline__ void wait_vm0_fence_sched() {
    asm volatile("s_waitcnt vmcnt(0)" ::: "memory");
    __builtin_amdgcn_sched_barrier(0);   // rule #18: pin MFMA after the wait
}

// one LSTM gate-group: zz = 4 raw gate pre-activations, c updated in place
static __device__ __forceinline__ u16 gate_apply(ushort4 zz, float b0, float b1,
                                                 float b2, float b3, float& c) {
    float gf = fast_sigmoid(bf2f(zz.x) + b0);
    float gi = fast_sigmoid(bf2f(zz.y) + b1);
    float gc = fast_tanh(bf2f(zz.z) + b2);
    float go = fast_sigmoid(bf2f(zz.w) + b3);
    float cn = gf * c + gi * gc;
    c = cn;
    return f2bf(go * fast_tanh(cn));
}

// dtype detector (fp32 vs bf16 buffers) — deterministic, graph-capture safe.
static __device__ __forceinline__ int detect_fp32(const uint* w, int nwords) {
    int hits = 0;
    for (int i = 0; i < nwords; ++i) { uint e = (w[i] >> 7) & 0xffu; hits += (e >= 0x80u); }
    return hits > (nwords >> 3);
}
static __device__ __forceinline__ u16 load_bf(const void* p, int i, int fp32) {
    return fp32 ? f2bf(((const float*)p)[i]) : ((const u16*)p)[i];
}

// Fragment-ordered weight pack (unchanged layout):
//   wp[((w*KSTEPS + ks)*4 + nt)*512 + lane*8 + j]
__global__ void pack_w(const void* wf, const void* wi, const void* wc, const void* wo,
                       const void* bbf, const void* bbi, const void* bbc, const void* bbo,
                       u16* __restrict__ wp, u16* __restrict__ bp, int K, int KSTEPS) {
    __shared__ int sfp;
    if (threadIdx.x == 0) sfp = detect_fp32((const uint*)wf, 256);
    __syncthreads();
    const int fp32 = sfp;
    int w = blockIdx.x / KSTEPS, ks = blockIdx.x % KSTEPS;
    int nt = threadIdx.x >> 6, lane = threadIdx.x & 63;
    int c16 = lane & 15, q = lane >> 4;
    int n = w * 64 + nt * 16 + c16;
    int u = n >> 2, g = n & 3;
    const void* W = (g == 0) ? wf : (g == 1) ? wi : (g == 2) ? wc : wo;
    union { u16 v[8]; uint4 u4; } tmp;
#pragma unroll
    for (int j = 0; j < 8; ++j) {
        int k = ks * 32 + q * 8 + j;
        tmp.v[j] = (k < K) ? load_bf(W, k * 256 + u, fp32) : (u16)0;
    }
    *(uint4*)(wp + ((w * KSTEPS + ks) * 4 + nt) * 512 + lane * 8) = tmp.u4;
    if (ks == 0 && threadIdx.x < 64) {
        int n2 = w * 64 + threadIdx.x;
        int g2 = n2 & 3;
        const void* B = (g2 == 0) ? bbf : (g2 == 1) ? bbi : (g2 == 2) ? bbc : bbo;
        bp[n2] = load_bf(B, n2 >> 2, fp32);
    }
}

// Pack embedding table + w_out/b_out; zero h-exchange buffers + barrier flags
// and counters (re-zeroed every launch/replay so barriers restart cleanly).
__global__ void pack_misc(const void* emb, const void* w_out, const void* b_out,
                          u16* __restrict__ embp, u16* __restrict__ wob,
                          u16* __restrict__ bob, uint* __restrict__ hzero) {
    __shared__ int sfp;
    if (threadIdx.x == 0) sfp = detect_fp32((const uint*)emb, 256);
    __syncthreads();
    const int fp32 = sfp;
    int gid = blockIdx.x * blockDim.x + threadIdx.x;
    int stride = gridDim.x * blockDim.x;
    for (int i = gid; i < 1000000; i += stride)
        embp[i] = load_bf(emb, i, fp32);
    // zero h1g (1MB) + h2g (1MB) + flags/counters (16 groups x 64 uints)
    for (int i = gid; i < 525312; i += stride) hzero[i] = 0;
    if (blockIdx.x == 0) {
        __shared__ int sfp2;
        if (threadIdx.x == 0) sfp2 = detect_fp32((const uint*)w_out, 128);
        __syncthreads();
        if (threadIdx.x < 256) wob[threadIdx.x] = load_bf(w_out, threadIdx.x, sfp2);
        if (threadIdx.x == 0) bob[0] = load_bf(b_out, 0, sfp2);
    }
}

// Row-group barrier: fast path fully inside the XCD's L2, with a coherent
// LLC-atomic safety net so it can NEVER hang.
// Arrival (tid0): plain-store phase into this block's flag slot (write-through
// L1 -> shared XCD L2) AND fire-and-forget a device-scope atomic increment of
// the row-group counter (LLC; off critical path).
// Wait (wave 0): poll the 16 flags with sc0 loads (XCD-L2 hits, ~250 cyc).
// Every 64 fast polls, check the coherent counter — if the block->XCD mapping
// assumption ever breaks (stale flag line in a peer L2), the counter still
// releases the barrier (degrades to round-5 behavior instead of deadlocking).
// Layout per row-group (256B): flags[0..15] on line 0, counter at +32 (line 1).
static __device__ __forceinline__ void rg_barrier(uint* grp, int gself,
                                                  uint phase, int tid) {
    asm volatile("s_waitcnt vmcnt(0)" ::: "memory");
    __syncthreads();                 // all waves' global stores are in L2
    if (tid < 64) {
        uint* cnt = grp + 32;
        if (tid == 0) {
            grp[gself] = phase;      // fast flag (XCD L2)
            __hip_atomic_fetch_add(cnt, 1u, __ATOMIC_RELAXED,
                                   __HIP_MEMORY_SCOPE_AGENT);   // safety net
        }
        const uint* fp = grp + (tid & 15);
        bool done = false;
        do {
#pragma unroll 1
            for (int k = 0; k < 64; ++k) {
                uint v;
                asm volatile("global_load_dword %0, %1, off sc0\n\t"
                             "s_waitcnt vmcnt(0)"
                             : "=v"(v) : "v"(fp) : "memory");
                if (__all((int)(v >= phase))) { done = true; break; }
            }
            if (!done)
                done = (__hip_atomic_load(cnt, __ATOMIC_RELAXED,
                                          __HIP_MEMORY_SCOPE_AGENT) >= 16u * phase);
        } while (!done);
    }
    __syncthreads();
}

// Persistent-weight LSTM, merged-GEMM pipeline.
// Grid 256 = 16 row-groups (r) x 16 unit-groups (g); block = 1024 thr (16 waves).
// Weight slices LDS-resident for all 80 steps. Per iteration i (after the
// barrier publishing h1(i), h2(i-1)): ONE batch of 16 sc0 A-loads feeds BOTH
// z2(i) (K=512) and z1(i+1) (K=356, shares the h1(i) fragments), then
// gates2(i)+gates1(i+1) store h2(i),h1(i+1), then ONE barrier. 80 barriers
// total; per-step sync cost ~1 drain + 2 syncthreads + 1 L2-flag spin.
#define HROWSTRIDE 256
#define HBUFSZ 262144   // 1024*256 u16 per parity

__global__ void __launch_bounds__(1024, 1)
lstm_kernel(const int* __restrict__ tokens, const u16* __restrict__ embp,
            const u16* __restrict__ wp1, const u16* __restrict__ b1p,
            const u16* __restrict__ wp2, const u16* __restrict__ b2p,
            const u16* __restrict__ wob, const u16* __restrict__ bob,
            u16* __restrict__ h1g, u16* __restrict__ h2g,
            uint* __restrict__ flags, float* __restrict__ out) {
    __shared__ __align__(16) u16 w1s[12 * 4 * 512];  // 49152 B  L1 weight slice
    __shared__ __align__(16) u16 w2s[16 * 4 * 512];  // 65536 B  L2 weight slice
    __shared__ __align__(16) u16 xtile[64 * 128];    // 16384 B  x_t (pad zero)
    __shared__ __align__(16) u16 scr[16 * 640];      // 20480 B  per-wave z2|z1
    // 151552 B total -> 1 block/CU, 256 blocks co-resident

    const int tid = threadIdx.x;
    const int bid = blockIdx.x;
    const int r = (bid & 7) + ((bid >> 7) << 3);  // row-group 0..15 (XCD-affine)
    const int g = (bid >> 3) & 15;                // unit-group 0..15
    const int lane = tid & 63;
    const int wv = tid >> 6;
    const int mt = wv >> 2, nt = wv & 3;          // wave -> (row-tile, col-tile)
    const int c16 = lane & 15, q = lane >> 4;
    const int grow0 = r * 64;

    const int rrg = tid >> 4;      // gate phase: local row 0..63
    const int ul = tid & 15;       // local unit
    const int gu = g * 16 + ul;    // global unit

    // ---- one-time: weights -> LDS, zero xtile pad, x(0), biases ----
    {
        const uint4* s1 = (const uint4*)(wp1 + g * (12 * 4 * 512));
        uint4* d1 = (uint4*)w1s;
        for (int i = tid; i < 3072; i += 1024) d1[i] = s1[i];
        const uint4* s2 = (const uint4*)(wp2 + g * (16 * 4 * 512));
        uint4* d2 = (uint4*)w2s;
        for (int i = tid; i < 4096; i += 1024) d2[i] = s2[i];
        uint* xz = (uint*)xtile;
        for (int i = tid; i < 4096; i += 1024) xz[i] = 0;
    }
    __syncthreads();
    for (int item = tid; item < 1600; item += 1024) {
        int rr = item / 25, s = item % 25;
        int tok = tokens[(grow0 + rr) * 80 + 0];
        *(ushort4*)(xtile + rr * 128 + s * 4) = *(const ushort4*)(embp + tok * 100 + s * 4);
    }
    ushort4 bw1 = *(const ushort4*)(b1p + gu * 4);
    ushort4 bw2 = *(const ushort4*)(b2p + gu * 4);
    const float b1f0 = bf2f(bw1.x), b1f1 = bf2f(bw1.y), b1f2 = bf2f(bw1.z), b1f3 = bf2f(bw1.w);
    const float b2f0 = bf2f(bw2.x), b2f1 = bf2f(bw2.y), b2f2 = bf2f(bw2.z), b2f3 = bf2f(bw2.w);
    float c1 = 0.f, c2 = 0.f;
    uint* myflags = flags + r * 64;    // 256B-padded per row-group
    uint phase = 0;
    __syncthreads();                   // x(0) visible

    const int arow = (grow0 + mt * 16 + c16) * HROWSTRIDE + q * 8;
    const u16* xp = xtile + (mt * 16 + c16) * 128 + q * 8;
    const u16* bp1 = w1s + nt * 512 + lane * 8;
    const u16* bp2 = w2s + nt * 512 + lane * 8;
    u16* swv = scr + wv * 640;         // [0..319]=z2, [320..639]=z1
    const u16* sv2 = scr + ((rrg >> 4) * 4 + (ul >> 2)) * 640 + (rrg & 15) * 20 + (ul & 3) * 4;
    const u16* sv1 = sv2 + 320;

    // ---- prologue: z1(0) = [0 | x0] @ W1 (h-part is zero -> x-MFMAs only) ----
    {
        f32x4 acc = (f32x4){0.f, 0.f, 0.f, 0.f};
#pragma unroll
        for (int ks = 8; ks < 12; ++ks)
            acc = __builtin_amdgcn_mfma_f32_16x16x32_bf16(
                as_bf16x8(*(const uint4*)(xp + (ks - 8) * 32)),
                as_bf16x8(*(const uint4*)(bp1 + ks * 2048)), acc, 0, 0, 0);
#pragma unroll
        for (int j = 0; j < 4; ++j) swv[320 + (q * 4 + j) * 20 + c16] = f2bf(acc[j]);
    }
    __syncthreads();
    {
        ushort4 zz = *(const ushort4*)sv1;
        u16 hb = gate_apply(zz, b1f0, b1f1, b1f2, b1f3, c1);
        h1g[0 * HBUFSZ + (grow0 + rrg) * HROWSTRIDE + gu] = hb;   // h1(0) parity 0
    }
    for (int item = tid; item < 1600; item += 1024) {             // x(1)
        int rr = item / 25, s = item % 25;
        int tok = tokens[(grow0 + rr) * 80 + 1];
        *(ushort4*)(xtile + rr * 128 + s * 4) = *(const ushort4*)(embp + tok * 100 + s * 4);
    }
    ++phase;
    rg_barrier(myflags, g, phase, tid);   // publish h1(0)

    // ---- main loop: iteration i computes z2(i) + z1(i+1) ----
#pragma unroll 1
    for (int i = 0; i < 79; ++i) {
        const int p_h2r = (i + 1) & 1;   // parity of h2(i-1)
        const int p_h1r = i & 1;         // parity of h1(i)

        u32x4 ag[16];
        {
            const u16* ap2 = h2g + p_h2r * HBUFSZ + arow;
            const u16* ap1 = h1g + p_h1r * HBUFSZ + arow;
#pragma unroll
            for (int ks = 0; ks < 8; ++ks) ag[ks] = load_b128_sc0(ap2 + ks * 32);
#pragma unroll
            for (int ks = 0; ks < 8; ++ks) ag[8 + ks] = load_b128_sc0(ap1 + ks * 32);
        }
        wait_vm0_fence_sched();

        // z2(i): K=512, A = [h2(i-1) | h1(i)]
        f32x4 acc2 = (f32x4){0.f, 0.f, 0.f, 0.f};
#pragma unroll
        for (int ks = 0; ks < 16; ++ks)
            acc2 = __builtin_amdgcn_mfma_f32_16x16x32_bf16(
                as_bf16x8v(ag[ks]), as_bf16x8(*(const uint4*)(bp2 + ks * 2048)), acc2, 0, 0, 0);
        // z1(i+1): K=356, A = [h1(i) | x(i+1)] — shares ag[8..15]
        f32x4 acc1 = (f32x4){0.f, 0.f, 0.f, 0.f};
#pragma unroll
        for (int ks = 0; ks < 8; ++ks)
            acc1 = __builtin_amdgcn_mfma_f32_16x16x32_bf16(
                as_bf16x8v(ag[8 + ks]), as_bf16x8(*(const uint4*)(bp1 + ks * 2048)), acc1, 0, 0, 0);
#pragma unroll
        for (int ks = 8; ks < 12; ++ks)
            acc1 = __builtin_amdgcn_mfma_f32_16x16x32_bf16(
                as_bf16x8(*(const uint4*)(xp + (ks - 8) * 32)),
                as_bf16x8(*(const uint4*)(bp1 + ks * 2048)), acc1, 0, 0, 0);
#pragma unroll
        for (int j = 0; j < 4; ++j) {
            swv[(q * 4 + j) * 20 + c16] = f2bf(acc2[j]);
            swv[320 + (q * 4 + j) * 20 + c16] = f2bf(acc1[j]);
        }

        // early-issue x(i+2) gathers (land after the sync, hide L2 latency)
        int rr0 = tid / 25, s0 = tid % 25;
        int it1 = tid + 1024;
        int rr1 = it1 / 25, s1 = it1 % 25;
        bool xact = (i <= 77);
        bool act1 = xact && (it1 < 1600);
        ushort4 xv0, xv1;
        if (xact) {
            int tok0 = tokens[(grow0 + rr0) * 80 + i + 2];
            xv0 = *(const ushort4*)(embp + tok0 * 100 + s0 * 4);
        }
        if (act1) {
            int tok1 = tokens[(grow0 + rr1) * 80 + i + 2];
            xv1 = *(const ushort4*)(embp + tok1 * 100 + s1 * 4);
        }
        __syncthreads();   // z's visible; MFMA xtile reads done

        // gates2(i) -> h2(i);  gates1(i+1) -> h1(i+1)
        {
            ushort4 z2 = *(const ushort4*)sv2;
            u16 h2b = gate_apply(z2, b2f0, b2f1, b2f2, b2f3, c2);
            h2g[(i & 1) * HBUFSZ + (grow0 + rrg) * HROWSTRIDE + gu] = h2b;
            ushort4 z1 = *(const ushort4*)sv1;
            u16 h1b = gate_apply(z1, b1f0, b1f1, b1f2, b1f3, c1);
            h1g[((i + 1) & 1) * HBUFSZ + (grow0 + rrg) * HROWSTRIDE + gu] = h1b;
        }
        if (xact) *(ushort4*)(xtile + rr0 * 128 + s0 * 4) = xv0;
        if (act1) *(ushort4*)(xtile + rr1 * 128 + s1 * 4) = xv1;

        ++phase;
        rg_barrier(myflags, g, phase, tid);   // publish h2(i), h1(i+1)
    }

    // ---- epilogue: z2(79), gates2(79) ----
    {
        u32x4 ag[16];
        const u16* ap2 = h2g + 0 * HBUFSZ + arow;   // h2(78) parity 0
        const u16* ap1 = h1g + 1 * HBUFSZ + arow;   // h1(79) parity 1
#pragma unroll
        for (int ks = 0; ks < 8; ++ks) ag[ks] = load_b128_sc0(ap2 + ks * 32);
#pragma unroll
        for (int ks = 0; ks < 8; ++ks) ag[8 + ks] = load_b128_sc0(ap1 + ks * 32);
        wait_vm0_fence_sched();
        f32x4 acc2 = (f32x4){0.f, 0.f, 0.f, 0.f};
#pragma unroll
        for (int ks = 0; ks < 16; ++ks)
            acc2 = __builtin_amdgcn_mfma_f32_16x16x32_bf16(
                as_bf16x8v(ag[ks]), as_bf16x8(*(const uint4*)(bp2 + ks * 2048)), acc2, 0, 0, 0);
#pragma unroll
        for (int j = 0; j < 4; ++j) swv[(q * 4 + j) * 20 + c16] = f2bf(acc2[j]);
    }
    __syncthreads();
    {
        ushort4 z2 = *(const ushort4*)sv2;
        u16 h2b = gate_apply(z2, b2f0, b2f1, b2f2, b2f3, c2);
        h2g[1 * HBUFSZ + (grow0 + rrg) * HROWSTRIDE + gu] = h2b;  // h2(79) parity 1
    }
    ++phase;
    rg_barrier(myflags, g, phase, tid);   // publish h2(79)

    // ---- output: sigmoid(h2 @ w_out + b_out), fp32 store (g==0 blocks) ----
    if (g == 0) {
        const u16* h2f = h2g + HBUFSZ;
        int rr = tid >> 4, s = tid & 15;
        const u16* hp = h2f + (grow0 + rr) * HROWSTRIDE + s * 16;
        u32x4 hv0 = load_b128_sc0(hp);
        u32x4 hv1 = load_b128_sc0(hp + 8);
        wait_vm0_fence_sched();
        const u16* wq = wob + s * 16;
        union { u32x4 v[2]; u16 h[16]; } hu; hu.v[0] = hv0; hu.v[1] = hv1;
        float dot = 0.f;
#pragma unroll
        for (int i = 0; i < 16; ++i) dot += bf2f(hu.h[i]) * bf2f(wq[i]);
        float* ps = (float*)scr;
        ps[rr * 16 + s] = dot;
        __syncthreads();
        if (tid < 64) {
            float ssum = 0.f;
            for (int i = 0; i < 16; ++i) ssum += ps[tid * 16 + i];
            out[grow0 + tid] = fast_sigmoid(ssum + bf2f(bob[0]));
        }
    }
}

extern "C" void kernel_launch(void* const* d_in, const int* in_sizes, int n_in,
                              void* d_out, int out_size, void* d_ws, size_t ws_size,
                              hipStream_t stream) {
    const int* tokens = (const int*)d_in[0];
    const void* emb = d_in[1];
    const void* wf1 = d_in[2];  const void* bf1_ = d_in[3];
    const void* wi1 = d_in[4];  const void* bi1_ = d_in[5];
    const void* wc1 = d_in[6];  const void* bc1_ = d_in[7];
    const void* wo1 = d_in[8];  const void* bo1_ = d_in[9];
    const void* wf2 = d_in[10]; const void* bf2_ = d_in[11];
    const void* wi2 = d_in[12]; const void* bi2_ = d_in[13];
    const void* wc2 = d_in[14]; const void* bc2_ = d_in[15];
    const void* wo2 = d_in[16]; const void* bo2_ = d_in[17];
    const void* w_out = d_in[18];
    const void* b_out = d_in[19];

    u16* wp1 = (u16*)d_ws;                 // 393216
    u16* wp2 = wp1 + 16 * 12 * 4 * 512;    // 524288
    u16* b1p = wp2 + 16 * 16 * 4 * 512;    // 1024
    u16* b2p = b1p + 1024;                 // 1024
    u16* wob = b2p + 1024;                 // 256
    u16* bob = wob + 256;                  // 8 (pad)
    u16* embp = bob + 8;                   // 1,000,000 (16B-aligned)
    u16* h1g = embp + 1000000;             // 2 x 1024 x 256
    u16* h2g = h1g + 2 * 262144;           // 2 x 1024 x 256
    uint* flags = (uint*)(h2g + 2 * 262144); // 16 x 64 uints (256B/row-group)

    pack_w<<<dim3(16 * 12), dim3(256), 0, stream>>>(wf1, wi1, wc1, wo1, bf1_, bi1_, bc1_, bo1_,
                                                    wp1, b1p, 356, 12);
    pack_w<<<dim3(16 * 16), dim3(256), 0, stream>>>(wf2, wi2, wc2, wo2, bf2_, bi2_, bc2_, bo2_,
                                                    wp2, b2p, 512, 16);
    pack_misc<<<dim3(512), dim3(256), 0, stream>>>(emb, w_out, b_out, embp, wob, bob, (uint*)h1g);
    lstm_kernel<<<dim3(256), dim3(1024), 0, stream>>>(tokens, embp, wp1, b1p, wp2, b2p,
                                                      wob, bob, h1g, h2g, flags, (float*)d_out);
}

// Round 8
// 963.934 us; speedup vs baseline: 1.3167x; 1.3167x over previous
//
#include <hip/hip_runtime.h>

typedef unsigned short u16;
typedef unsigned int uint;

using f32x4 = __attribute__((ext_vector_type(4))) float;
using bf16x8 = __attribute__((ext_vector_type(8))) __bf16;
using u32x4 = __attribute__((ext_vector_type(4))) uint;

static __device__ __forceinline__ bf16x8 as_bf16x8(uint4 u) {
    union { uint4 a; bf16x8 b; } c; c.a = u; return c.b;
}
static __device__ __forceinline__ bf16x8 as_bf16x8v(u32x4 u) {
    union { u32x4 a; bf16x8 b; } c; c.a = u; return c.b;
}
static __device__ __forceinline__ float bf2f(u16 h) {
    union { uint u; float f; } c; c.u = ((uint)h) << 16; return c.f;
}
static __device__ __forceinline__ u16 f2bf(float f) {
    union { float f; uint u; } c; c.f = f;
    uint u = c.u;
    return (u16)((u + 0x7fffu + ((u >> 16) & 1u)) >> 16);
}
static __device__ __forceinline__ float fast_sigmoid(float x) {
    x = fminf(30.f, fmaxf(-30.f, x));
    return __builtin_amdgcn_rcpf(1.0f + __builtin_amdgcn_exp2f(x * -1.44269504f));
}
static __device__ __forceinline__ float fast_tanh(float x) {
    x = fminf(15.f, fmaxf(-15.f, x));
    return 1.0f - 2.0f * __builtin_amdgcn_rcpf(1.0f + __builtin_amdgcn_exp2f(x * 2.88539008f));
}

// L1-bypassing 16B load (sc0): reads the XCD-shared L2 directly, so peer-block
// writes (write-through L1 -> L2) are visible without agent-scope fences.
static __device__ __forceinline__ u32x4 load_b128_sc0(const u16* p) {
    u32x4 r;
    asm volatile("global_load_dwordx4 %0, %1, off sc0" : "=v"(r) : "v"(p) : "memory");
    return r;
}
static __device__ __forceinline__ void wait_vm0_fence_sched() {
    asm volatile("s_waitcnt vmcnt(0)" ::: "memory");
    __builtin_amdgcn_sched_barrier(0);   // rule #18: pin MFMA after the wait
}

static __device__ __forceinline__ u16 gate_apply(ushort4 zz, float b0, float b1,
                                                 float b2, float b3, float& c) {
    float gf = fast_sigmoid(bf2f(zz.x) + b0);
    float gi = fast_sigmoid(bf2f(zz.y) + b1);
    float gc = fast_tanh(bf2f(zz.z) + b2);
    float go = fast_sigmoid(bf2f(zz.w) + b3);
    float cn = gf * c + gi * gc;
    c = cn;
    return f2bf(go * fast_tanh(cn));
}

// dtype detector (fp32 vs bf16 buffers) — deterministic, graph-capture safe.
static __device__ __forceinline__ int detect_fp32(const uint* w, int nwords) {
    int hits = 0;
    for (int i = 0; i < nwords; ++i) { uint e = (w[i] >> 7) & 0xffu; hits += (e >= 0x80u); }
    return hits > (nwords >> 3);
}
static __device__ __forceinline__ u16 load_bf(const void* p, int i, int fp32) {
    return fp32 ? f2bf(((const float*)p)[i]) : ((const u16*)p)[i];
}

// Fragment-ordered weight pack (unchanged layout):
//   wp[((w*KSTEPS + ks)*4 + nt)*512 + lane*8 + j]
__global__ void pack_w(const void* wf, const void* wi, const void* wc, const void* wo,
                       const void* bbf, const void* bbi, const void* bbc, const void* bbo,
                       u16* __restrict__ wp, u16* __restrict__ bp, int K, int KSTEPS) {
    __shared__ int sfp;
    if (threadIdx.x == 0) sfp = detect_fp32((const uint*)wf, 256);
    __syncthreads();
    const int fp32 = sfp;
    int w = blockIdx.x / KSTEPS, ks = blockIdx.x % KSTEPS;
    int nt = threadIdx.x >> 6, lane = threadIdx.x & 63;
    int c16 = lane & 15, q = lane >> 4;
    int n = w * 64 + nt * 16 + c16;
    int u = n >> 2, g = n & 3;
    const void* W = (g == 0) ? wf : (g == 1) ? wi : (g == 2) ? wc : wo;
    union { u16 v[8]; uint4 u4; } tmp;
#pragma unroll
    for (int j = 0; j < 8; ++j) {
        int k = ks * 32 + q * 8 + j;
        tmp.v[j] = (k < K) ? load_bf(W, k * 256 + u, fp32) : (u16)0;
    }
    *(uint4*)(wp + ((w * KSTEPS + ks) * 4 + nt) * 512 + lane * 8) = tmp.u4;
    if (ks == 0 && threadIdx.x < 64) {
        int n2 = w * 64 + threadIdx.x;
        int g2 = n2 & 3;
        const void* B = (g2 == 0) ? bbf : (g2 == 1) ? bbi : (g2 == 2) ? bbc : bbo;
        bp[n2] = load_bf(B, n2 >> 2, fp32);
    }
}

// Pack embedding table + w_out/b_out; zero h-exchange buffers + barrier flags
// (re-zeroed every launch/replay so barriers restart cleanly).
__global__ void pack_misc(const void* emb, const void* w_out, const void* b_out,
                          u16* __restrict__ embp, u16* __restrict__ wob,
                          u16* __restrict__ bob, uint* __restrict__ hzero) {
    __shared__ int sfp;
    if (threadIdx.x == 0) sfp = detect_fp32((const uint*)emb, 256);
    __syncthreads();
    const int fp32 = sfp;
    int gid = blockIdx.x * blockDim.x + threadIdx.x;
    int stride = gridDim.x * blockDim.x;
    for (int i = gid; i < 1000000; i += stride)
        embp[i] = load_bf(emb, i, fp32);
    // zero h1g (1MB) + h2g (1MB) + flags (2 chains x 8 groups x 64 uints)
    for (int i = gid; i < 525312; i += stride) hzero[i] = 0;
    if (blockIdx.x == 0) {
        __shared__ int sfp2;
        if (threadIdx.x == 0) sfp2 = detect_fp32((const uint*)w_out, 128);
        __syncthreads();
        if (threadIdx.x < 256) wob[threadIdx.x] = load_bf(w_out, threadIdx.x, sfp2);
        if (threadIdx.x == 0) bob[0] = load_bf(b_out, 0, sfp2);
    }
}

// Split barrier (arrive early / wait late) so flag propagation ages under the
// sibling chain's compute. Fast path: XCD-L2 flags (plain write-through store,
// sc0 polls). Safety net: LLC atomic counter checked every 64 polls -> can
// never hang even if the block->XCD mapping assumption breaks.
static __device__ __forceinline__ void rg_arrive(uint* grp, int gself,
                                                 uint phase, int tid) {
    asm volatile("s_waitcnt vmcnt(0)" ::: "memory");   // h-stores in L2
    __syncthreads();
    if (tid == 0) {
        grp[gself] = phase;
        __hip_atomic_fetch_add(grp + 32, 1u, __ATOMIC_RELAXED,
                               __HIP_MEMORY_SCOPE_AGENT);
    }
}
static __device__ __forceinline__ void rg_wait(uint* grp, uint phase, int tid) {
    if (tid < 64) {
        const uint* fp = grp + (tid & 15);
        uint* cnt = grp + 32;
        bool done = false;
        do {
#pragma unroll 1
            for (int k = 0; k < 64; ++k) {
                uint v;
                asm volatile("global_load_dword %0, %1, off sc0\n\t"
                             "s_waitcnt vmcnt(0)"
                             : "=v"(v) : "v"(fp) : "memory");
                if (__all((int)(v >= phase))) { done = true; break; }
            }
            if (!done)
                done = (__hip_atomic_load(cnt, __ATOMIC_RELAXED,
                                          __HIP_MEMORY_SCOPE_AGENT) >= 16u * phase);
        } while (!done);
    }
    __syncthreads();
}

// Persistent-weight LSTM, TWO phase-shifted 64-row chains per block.
// Grid 128 = 8 chain-pairs (r2 = bid&7, XCD-affine) x 16 unit-groups (g).
// Block (r2,g): units g*16..+15 for rows r2*128..+127 (chain A = first 64,
// chain B = second 64). While chain A's exchange latency elapses, chain B
// computes, and vice versa. h layout is BLOCK-MAJOR: h[par][ch][r2][g][row][ul]
// -> each 128B line written fully-coalesced by exactly ONE CU (no partial-line
// sharing), read as 16B lane chunks.
#define CSLAB 16384   // u16 per (par,ch,r2) h-slab: 16 g x 64 rows x 16 ul

__global__ void __launch_bounds__(1024, 1)
lstm_kernel(const int* __restrict__ tokens, const u16* __restrict__ embp,
            const u16* __restrict__ wp1, const u16* __restrict__ b1p,
            const u16* __restrict__ wp2, const u16* __restrict__ b2p,
            const u16* __restrict__ wob, const u16* __restrict__ bob,
            u16* __restrict__ h1g, u16* __restrict__ h2g,
            uint* __restrict__ flags, float* __restrict__ out) {
    __shared__ __align__(16) u16 w1s[12 * 4 * 512];  // 49152 B
    __shared__ __align__(16) u16 w2s[16 * 4 * 512];  // 65536 B
    __shared__ __align__(16) u16 scr[16 * 640];      // 20480 B per-wave z2|z1
    // 135168 B total -> 1 block/CU

    const int tid = threadIdx.x;
    const int bid = blockIdx.x;
    const int r2 = bid & 7;          // chain-pair 0..7 (XCD-affine)
    const int g = bid >> 3;          // unit-group 0..15
    const int lane = tid & 63;
    const int wv = tid >> 6;
    const int mt = wv >> 2, nt = wv & 3;
    const int c16 = lane & 15, q = lane >> 4;
    const int rrf = mt * 16 + c16;               // A-fragment row 0..63
    const int loff = (q >> 1) * 1024 + rrf * 16 + (q & 1) * 8;  // lane h-slab offset
    const int rrg = tid >> 4;        // gate phase: local row 0..63
    const int ul = tid & 15;
    const int gu = g * 16 + ul;
    const int widx = g * 1024 + rrg * 16 + ul;   // gate-store offset in slab

    // ---- one-time: weights -> LDS, biases ----
    {
        const uint4* s1 = (const uint4*)(wp1 + g * (12 * 4 * 512));
        uint4* d1 = (uint4*)w1s;
        for (int i = tid; i < 3072; i += 1024) d1[i] = s1[i];
        const uint4* s2 = (const uint4*)(wp2 + g * (16 * 4 * 512));
        uint4* d2 = (uint4*)w2s;
        for (int i = tid; i < 4096; i += 1024) d2[i] = s2[i];
    }
    ushort4 bw1 = *(const ushort4*)(b1p + gu * 4);
    ushort4 bw2 = *(const ushort4*)(b2p + gu * 4);
    const float b1f0 = bf2f(bw1.x), b1f1 = bf2f(bw1.y), b1f2 = bf2f(bw1.z), b1f3 = bf2f(bw1.w);
    const float b2f0 = bf2f(bw2.x), b2f1 = bf2f(bw2.y), b2f2 = bf2f(bw2.z), b2f3 = bf2f(bw2.w);
    float c1s[2] = {0.f, 0.f}, c2s[2] = {0.f, 0.f};
    uint ph[2] = {0u, 0u};
    uint* fgrp[2] = {flags + (0 * 8 + r2) * 64, flags + (1 * 8 + r2) * 64};
    __syncthreads();

    const u16* bp1 = w1s + nt * 512 + lane * 8;
    const u16* bp2 = w2s + nt * 512 + lane * 8;
    u16* swv = scr + wv * 640;                   // [0..319]=z2, [320..639]=z1
    const u16* sv2 = scr + ((rrg >> 4) * 4 + (ul >> 2)) * 640 + (rrg & 15) * 20 + (ul & 3) * 4;
    const u16* sv1 = sv2 + 320;

    // per-chain x-fragment loader (direct from embp; cols>=100 hit zero weights)
    ushort4 xlo[4], xhi[4];
#define LOAD_X(ch, t)                                                          \
    {                                                                          \
        int row = r2 * 128 + (ch) * 64 + rrf;                                  \
        int tok = tokens[row * 80 + (t)];                                      \
        const u16* xb = embp + tok * 100 + q * 8;                              \
        _Pragma("unroll")                                                      \
        for (int k2 = 0; k2 < 4; ++k2) {                                       \
            xlo[k2] = *(const ushort4*)(xb + k2 * 32);                         \
            xhi[k2] = *(const ushort4*)(xb + k2 * 32 + 4);                     \
        }                                                                      \
    }
#define XFRAG(k2) ({ union { ushort4 a[2]; bf16x8 v; } xu;                     \
                     xu.a[0] = xlo[k2]; xu.a[1] = xhi[k2]; xu.v; })

    // ---- prologue per chain: z1(0) = x(0)-part only; gates1 -> h1(0) ----
#pragma unroll 1
    for (int ch = 0; ch < 2; ++ch) {
        LOAD_X(ch, 0);
        f32x4 acc = (f32x4){0.f, 0.f, 0.f, 0.f};
#pragma unroll
        for (int k2 = 0; k2 < 4; ++k2)
            acc = __builtin_amdgcn_mfma_f32_16x16x32_bf16(
                XFRAG(k2), as_bf16x8(*(const uint4*)(bp1 + (8 + k2) * 2048)), acc, 0, 0, 0);
#pragma unroll
        for (int j = 0; j < 4; ++j) swv[320 + (q * 4 + j) * 20 + c16] = f2bf(acc[j]);
        __syncthreads();
        ushort4 zz = *(const ushort4*)sv1;
        u16 hb = gate_apply(zz, b1f0, b1f1, b1f2, b1f3, c1s[ch]);
        h1g[((0 * 2 + ch) * 8 + r2) * CSLAB + widx] = hb;       // h1(0) parity 0
        ++ph[ch];
        rg_arrive(fgrp[ch], g, ph[ch], tid);
    }

    // ---- main loop: iteration i = step i (L2) + step i+1 (L1), chains interleaved
#pragma unroll 1
    for (int i = 0; i < 79; ++i) {
        const int p_h2r = (i + 1) & 1, p_h1r = i & 1;
        const int p_h2w = i & 1, p_h1w = (i + 1) & 1;
#pragma unroll 1
        for (int ch = 0; ch < 2; ++ch) {
            LOAD_X(ch, i + 1);                    // issue before wait (barrier-independent)
            rg_wait(fgrp[ch], ph[ch], tid);       // h2(i-1), h1(i) published

            const u16* h2b = h2g + ((p_h2r * 2 + ch) * 8 + r2) * CSLAB + loff;
            const u16* h1b = h1g + ((p_h1r * 2 + ch) * 8 + r2) * CSLAB + loff;
            u32x4 ag[16];
#pragma unroll
            for (int ks = 0; ks < 8; ++ks) ag[ks] = load_b128_sc0(h2b + ks * 2048);
#pragma unroll
            for (int ks = 0; ks < 8; ++ks) ag[8 + ks] = load_b128_sc0(h1b + ks * 2048);
            wait_vm0_fence_sched();

            f32x4 acc2 = (f32x4){0.f, 0.f, 0.f, 0.f};
#pragma unroll
            for (int ks = 0; ks < 16; ++ks)
                acc2 = __builtin_amdgcn_mfma_f32_16x16x32_bf16(
                    as_bf16x8v(ag[ks]), as_bf16x8(*(const uint4*)(bp2 + ks * 2048)), acc2, 0, 0, 0);
            f32x4 acc1 = (f32x4){0.f, 0.f, 0.f, 0.f};
#pragma unroll
            for (int ks = 0; ks < 8; ++ks)
                acc1 = __builtin_amdgcn_mfma_f32_16x16x32_bf16(
                    as_bf16x8v(ag[8 + ks]), as_bf16x8(*(const uint4*)(bp1 + ks * 2048)), acc1, 0, 0, 0);
#pragma unroll
            for (int k2 = 0; k2 < 4; ++k2)
                acc1 = __builtin_amdgcn_mfma_f32_16x16x32_bf16(
                    XFRAG(k2), as_bf16x8(*(const uint4*)(bp1 + (8 + k2) * 2048)), acc1, 0, 0, 0);
#pragma unroll
            for (int j = 0; j < 4; ++j) {
                swv[(q * 4 + j) * 20 + c16] = f2bf(acc2[j]);
                swv[320 + (q * 4 + j) * 20 + c16] = f2bf(acc1[j]);
            }
            __syncthreads();

            ushort4 z2 = *(const ushort4*)sv2;
            u16 h2b_ = gate_apply(z2, b2f0, b2f1, b2f2, b2f3, c2s[ch]);
            h2g[((p_h2w * 2 + ch) * 8 + r2) * CSLAB + widx] = h2b_;
            ushort4 z1 = *(const ushort4*)sv1;
            u16 h1b_ = gate_apply(z1, b1f0, b1f1, b1f2, b1f3, c1s[ch]);
            h1g[((p_h1w * 2 + ch) * 8 + r2) * CSLAB + widx] = h1b_;

            ++ph[ch];
            rg_arrive(fgrp[ch], g, ph[ch], tid);  // publish h2(i), h1(i+1)
        }
    }

    // ---- epilogue per chain: z2(79), gates2(79) ----
#pragma unroll 1
    for (int ch = 0; ch < 2; ++ch) {
        rg_wait(fgrp[ch], ph[ch], tid);           // h2(78) par0, h1(79) par1
        const u16* h2b = h2g + ((0 * 2 + ch) * 8 + r2) * CSLAB + loff;
        const u16* h1b = h1g + ((1 * 2 + ch) * 8 + r2) * CSLAB + loff;
        u32x4 ag[16];
#pragma unroll
        for (int ks = 0; ks < 8; ++ks) ag[ks] = load_b128_sc0(h2b + ks * 2048);
#pragma unroll
        for (int ks = 0; ks < 8; ++ks) ag[8 + ks] = load_b128_sc0(h1b + ks * 2048);
        wait_vm0_fence_sched();
        f32x4 acc2 = (f32x4){0.f, 0.f, 0.f, 0.f};
#pragma unroll
        for (int ks = 0; ks < 16; ++ks)
            acc2 = __builtin_amdgcn_mfma_f32_16x16x32_bf16(
                as_bf16x8v(ag[ks]), as_bf16x8(*(const uint4*)(bp2 + ks * 2048)), acc2, 0, 0, 0);
#pragma unroll
        for (int j = 0; j < 4; ++j) swv[(q * 4 + j) * 20 + c16] = f2bf(acc2[j]);
        __syncthreads();
        ushort4 z2 = *(const ushort4*)sv2;
        u16 h2b_ = gate_apply(z2, b2f0, b2f1, b2f2, b2f3, c2s[ch]);
        h2g[((1 * 2 + ch) * 8 + r2) * CSLAB + widx] = h2b_;     // h2(79) parity 1
        ++ph[ch];
        rg_arrive(fgrp[ch], g, ph[ch], tid);
    }
    rg_wait(fgrp[0], ph[0], tid);
    rg_wait(fgrp[1], ph[1], tid);

    // ---- output: sigmoid(h2 @ w_out + b_out) by g==0 blocks ----
    if (g == 0) {
#pragma unroll 1
        for (int ch = 0; ch < 2; ++ch) {
            const u16* base = h2g + ((1 * 2 + ch) * 8 + r2) * CSLAB;
            int rr = tid >> 4, s = tid & 15;
            const u16* hp = base + s * 1024 + rr * 16;
            u32x4 hv0 = load_b128_sc0(hp);
            u32x4 hv1 = load_b128_sc0(hp + 8);
            wait_vm0_fence_sched();
            const u16* wq = wob + s * 16;
            union { u32x4 v[2]; u16 h[16]; } hu; hu.v[0] = hv0; hu.v[1] = hv1;
            float dot = 0.f;
#pragma unroll
            for (int k = 0; k < 16; ++k) dot += bf2f(hu.h[k]) * bf2f(wq[k]);
            float* ps = (float*)scr;
            __syncthreads();                       // scr reuse across chains
            ps[rr * 16 + s] = dot;
            __syncthreads();
            if (tid < 64) {
                float ssum = 0.f;
                for (int k = 0; k < 16; ++k) ssum += ps[tid * 16 + k];
                out[r2 * 128 + ch * 64 + tid] = fast_sigmoid(ssum + bf2f(bob[0]));
            }
        }
    }
}

extern "C" void kernel_launch(void* const* d_in, const int* in_sizes, int n_in,
                              void* d_out, int out_size, void* d_ws, size_t ws_size,
                              hipStream_t stream) {
    const int* tokens = (const int*)d_in[0];
    const void* emb = d_in[1];
    const void* wf1 = d_in[2];  const void* bf1_ = d_in[3];
    const void* wi1 = d_in[4];  const void* bi1_ = d_in[5];
    const void* wc1 = d_in[6];  const void* bc1_ = d_in[7];
    const void* wo1 = d_in[8];  const void* bo1_ = d_in[9];
    const void* wf2 = d_in[10]; const void* bf2_ = d_in[11];
    const void* wi2 = d_in[12]; const void* bi2_ = d_in[13];
    const void* wc2 = d_in[14]; const void* bc2_ = d_in[15];
    const void* wo2 = d_in[16]; const void* bo2_ = d_in[17];
    const void* w_out = d_in[18];
    const void* b_out = d_in[19];

    u16* wp1 = (u16*)d_ws;                 // 393216
    u16* wp2 = wp1 + 16 * 12 * 4 * 512;    // 524288
    u16* b1p = wp2 + 16 * 16 * 4 * 512;    // 1024
    u16* b2p = b1p + 1024;                 // 1024
    u16* wob = b2p + 1024;                 // 256
    u16* bob = wob + 256;                  // 8 (pad)
    u16* embp = bob + 8;                   // 1,000,000 (16B-aligned)
    u16* h1g = embp + 1000000;             // 2par x 2ch x 8 x 16384 = 524288
    u16* h2g = h1g + 524288;               // same
    uint* flags = (uint*)(h2g + 524288);   // 2ch x 8 x 64 uints

    pack_w<<<dim3(16 * 12), dim3(256), 0, stream>>>(wf1, wi1, wc1, wo1, bf1_, bi1_, bc1_, bo1_,
                                                    wp1, b1p, 356, 12);
    pack_w<<<dim3(16 * 16), dim3(256), 0, stream>>>(wf2, wi2, wc2, wo2, bf2_, bi2_, bc2_, bo2_,
                                                    wp2, b2p, 512, 16);
    pack_misc<<<dim3(512), dim3(256), 0, stream>>>(emb, w_out, b_out, embp, wob, bob, (uint*)h1g);
    lstm_kernel<<<dim3(128), dim3(1024), 0, stream>>>(tokens, embp, wp1, b1p, wp2, b2p,
                                                      wob, bob, h1g, h2g, flags, (float*)d_out);
}

// Round 9
// 885.642 us; speedup vs baseline: 1.4331x; 1.0884x over previous
//
#include <hip/hip_runtime.h>

typedef unsigned short u16;
typedef unsigned int uint;

using f32x4 = __attribute__((ext_vector_type(4))) float;
using bf16x8 = __attribute__((ext_vector_type(8))) __bf16;
using u32x4 = __attribute__((ext_vector_type(4))) uint;

static __device__ __forceinline__ bf16x8 as_bf16x8(uint4 u) {
    union { uint4 a; bf16x8 b; } c; c.a = u; return c.b;
}
static __device__ __forceinline__ bf16x8 as_bf16x8v(u32x4 u) {
    union { u32x4 a; bf16x8 b; } c; c.a = u; return c.b;
}
static __device__ __forceinline__ float bf2f(u16 h) {
    union { uint u; float f; } c; c.u = ((uint)h) << 16; return c.f;
}
static __device__ __forceinline__ u16 f2bf(float f) {
    union { float f; uint u; } c; c.f = f;
    uint u = c.u;
    return (u16)((u + 0x7fffu + ((u >> 16) & 1u)) >> 16);
}
static __device__ __forceinline__ float fast_sigmoid(float x) {
    x = fminf(30.f, fmaxf(-30.f, x));
    return __builtin_amdgcn_rcpf(1.0f + __builtin_amdgcn_exp2f(x * -1.44269504f));
}
static __device__ __forceinline__ float fast_tanh(float x) {
    x = fminf(15.f, fmaxf(-15.f, x));
    return 1.0f - 2.0f * __builtin_amdgcn_rcpf(1.0f + __builtin_amdgcn_exp2f(x * 2.88539008f));
}

// L1-bypassing 16B load (sc0): reads the XCD-shared L2 directly, so peer-block
// writes (write-through L1 -> L2) are visible without agent-scope fences.
static __device__ __forceinline__ u32x4 load_b128_sc0(const u16* p) {
    u32x4 r;
    asm volatile("global_load_dwordx4 %0, %1, off sc0" : "=v"(r) : "v"(p) : "memory");
    return r;
}
static __device__ __forceinline__ void wait_vm0_fence_sched() {
    asm volatile("s_waitcnt vmcnt(0)" ::: "memory");
    __builtin_amdgcn_sched_barrier(0);   // rule #18: pin MFMA after the wait
}

// constant-index helpers (avoid runtime-indexed vectors -> scratch, rule #20)
static __device__ __forceinline__ float vext(f32x4 v, int i) {
    float r = v[0];
    r = (i == 1) ? v[1] : r;
    r = (i == 2) ? v[2] : r;
    r = (i == 3) ? v[3] : r;
    return r;
}
static __device__ __forceinline__ float sel4(float a0, float a1, float a2, float a3, int i) {
    float r = a0;
    r = (i == 1) ? a1 : r;
    r = (i == 2) ? a2 : r;
    r = (i == 3) ? a3 : r;
    return r;
}

// dtype detector (fp32 vs bf16 buffers) — deterministic, graph-capture safe.
static __device__ __forceinline__ int detect_fp32(const uint* w, int nwords) {
    int hits = 0;
    for (int i = 0; i < nwords; ++i) { uint e = (w[i] >> 7) & 0xffu; hits += (e >= 0x80u); }
    return hits > (nwords >> 3);
}
static __device__ __forceinline__ u16 load_bf(const void* p, int i, int fp32) {
    return fp32 ? f2bf(((const float*)p)[i]) : ((const u16*)p)[i];
}

// Fragment-ordered weight pack (unchanged layout):
//   wp[((w*KSTEPS + ks)*4 + nt)*512 + lane*8 + j]
__global__ void pack_w(const void* wf, const void* wi, const void* wc, const void* wo,
                       const void* bbf, const void* bbi, const void* bbc, const void* bbo,
                       u16* __restrict__ wp, u16* __restrict__ bp, int K, int KSTEPS) {
    __shared__ int sfp;
    if (threadIdx.x == 0) sfp = detect_fp32((const uint*)wf, 256);
    __syncthreads();
    const int fp32 = sfp;
    int w = blockIdx.x / KSTEPS, ks = blockIdx.x % KSTEPS;
    int nt = threadIdx.x >> 6, lane = threadIdx.x & 63;
    int c16 = lane & 15, q = lane >> 4;
    int n = w * 64 + nt * 16 + c16;
    int u = n >> 2, g = n & 3;
    const void* W = (g == 0) ? wf : (g == 1) ? wi : (g == 2) ? wc : wo;
    union { u16 v[8]; uint4 u4; } tmp;
#pragma unroll
    for (int j = 0; j < 8; ++j) {
        int k = ks * 32 + q * 8 + j;
        tmp.v[j] = (k < K) ? load_bf(W, k * 256 + u, fp32) : (u16)0;
    }
    *(uint4*)(wp + ((w * KSTEPS + ks) * 4 + nt) * 512 + lane * 8) = tmp.u4;
    if (ks == 0 && threadIdx.x < 64) {
        int n2 = w * 64 + threadIdx.x;
        int g2 = n2 & 3;
        const void* B = (g2 == 0) ? bbf : (g2 == 1) ? bbi : (g2 == 2) ? bbc : bbo;
        bp[n2] = load_bf(B, n2 >> 2, fp32);
    }
}

// Pack embedding table + w_out/b_out; zero h-exchange buffers + barrier flags.
__global__ void pack_misc(const void* emb, const void* w_out, const void* b_out,
                          u16* __restrict__ embp, u16* __restrict__ wob,
                          u16* __restrict__ bob, uint* __restrict__ hzero) {
    __shared__ int sfp;
    if (threadIdx.x == 0) sfp = detect_fp32((const uint*)emb, 256);
    __syncthreads();
    const int fp32 = sfp;
    int gid = blockIdx.x * blockDim.x + threadIdx.x;
    int stride = gridDim.x * blockDim.x;
    for (int i = gid; i < 1000000; i += stride)
        embp[i] = load_bf(emb, i, fp32);
    for (int i = gid; i < 525312; i += stride) hzero[i] = 0;
    if (blockIdx.x == 0) {
        __shared__ int sfp2;
        if (threadIdx.x == 0) sfp2 = detect_fp32((const uint*)w_out, 128);
        __syncthreads();
        if (threadIdx.x < 256) wob[threadIdx.x] = load_bf(w_out, threadIdx.x, sfp2);
        if (threadIdx.x == 0) bob[0] = load_bf(b_out, 0, sfp2);
    }
}

// Split barrier. Arrival: sc0 (coherent) flag store into XCD L2 + LLC atomic.
// Wait: poll flags (sc0) AND the coherent counter EVERY iteration — detection
// latency is min(flag path, ~600cyc LLC path) instead of riding a slow path
// for up to 64 polls. Can never hang.
static __device__ __forceinline__ void rg_arrive(uint* grp, int gself,
                                                 uint phase, int tid) {
    asm volatile("s_waitcnt vmcnt(0)" ::: "memory");   // h-stores in L2
    __syncthreads();
    if (tid == 0) {
        uint* slot = grp + gself;
        asm volatile("global_store_dword %0, %1, off sc0" :: "v"(slot), "v"(phase) : "memory");
        __hip_atomic_fetch_add(grp + 32, 1u, __ATOMIC_RELAXED,
                               __HIP_MEMORY_SCOPE_AGENT);
    }
}
static __device__ __forceinline__ void rg_wait(uint* grp, uint phase, int tid) {
    if (tid < 64) {
        const uint* fp = grp + (tid & 15);
        uint* cnt = grp + 32;
        while (true) {
            uint v;
            asm volatile("global_load_dword %0, %1, off sc0\n\t"
                         "s_waitcnt vmcnt(0)"
                         : "=v"(v) : "v"(fp) : "memory");
            if (__all((int)(v >= phase))) break;
            if (__hip_atomic_load(cnt, __ATOMIC_RELAXED,
                                  __HIP_MEMORY_SCOPE_AGENT) >= 16u * phase) break;
        }
    }
    __syncthreads();
}

// Persistent-weight LSTM, 2 phase-shifted 64-row chains per block, IN-WAVE
// gates (shuffle transpose; no scr LDS round-trip, 1 syncthreads/half-step).
// Grid 128 = 8 chain-pairs (r2 = bid&7, XCD-affine) x 16 unit-groups (g).
// h layout block-major: h[par][ch][r2][g][row][ul].
#define CSLAB 16384   // u16 per (par,ch,r2) h-slab: 16 g x 64 rows x 16 ul

__global__ void __launch_bounds__(1024, 1)
lstm_kernel(const int* __restrict__ tokens, const u16* __restrict__ embp,
            const u16* __restrict__ wp1, const u16* __restrict__ b1p,
            const u16* __restrict__ wp2, const u16* __restrict__ b2p,
            const u16* __restrict__ wob, const u16* __restrict__ bob,
            u16* __restrict__ h1g, u16* __restrict__ h2g,
            uint* __restrict__ flags, float* __restrict__ out) {
    __shared__ __align__(16) u16 w1s[12 * 4 * 512];   // 49152 B
    __shared__ __align__(16) u16 w2s[16 * 4 * 512];   // 65536 B
    __shared__ __align__(16) float outscr[1024];      // 4096 B (epilogue only)
    // 118784 B -> 1 block/CU

    const int tid = threadIdx.x;
    const int bid = blockIdx.x;
    const int r2 = bid & 7;          // chain-pair 0..7 (XCD-affine)
    const int g = bid >> 3;          // unit-group 0..15
    const int lane = tid & 63;
    const int wv = tid >> 6;
    const int mt = wv >> 2, nt = wv & 3;
    const int c16 = lane & 15, q = lane >> 4;
    const int rrf = mt * 16 + c16;                   // A-fragment row 0..63
    const int loff = (q >> 1) * 1024 + rrf * 16 + (q & 1) * 8;  // A-load offset

    // gate-lane mapping (in-wave): lane owns (unit, row):
    const int b = lane & 3;                          // gate-nibble id
    const int ulz = nt * 4 + ((lane & 15) >> 2);     // unit-local 0..15
    const int gunit = g * 16 + ulz;                  // global unit
    const int rloc = mt * 16 + q * 4 + b;            // row 0..63
    const int hidx = g * 1024 + rloc * 16 + ulz;     // h-store offset in slab

    // ---- one-time: weights -> LDS, biases (per gate-lane unit) ----
    {
        const uint4* s1 = (const uint4*)(wp1 + g * (12 * 4 * 512));
        uint4* d1 = (uint4*)w1s;
        for (int i = tid; i < 3072; i += 1024) d1[i] = s1[i];
        const uint4* s2 = (const uint4*)(wp2 + g * (16 * 4 * 512));
        uint4* d2 = (uint4*)w2s;
        for (int i = tid; i < 4096; i += 1024) d2[i] = s2[i];
    }
    ushort4 bl1 = *(const ushort4*)(b1p + gunit * 4);
    ushort4 bl2 = *(const ushort4*)(b2p + gunit * 4);
    const float b1f = bf2f(bl1.x), b1i = bf2f(bl1.y), b1c = bf2f(bl1.z), b1o = bf2f(bl1.w);
    const float b2f = bf2f(bl2.x), b2i = bf2f(bl2.y), b2c = bf2f(bl2.z), b2o = bf2f(bl2.w);
    float c1s[2] = {0.f, 0.f}, c2s[2] = {0.f, 0.f};
    uint ph[2] = {0u, 0u};
    uint* fgrp[2] = {flags + (0 * 8 + r2) * 64, flags + (1 * 8 + r2) * 64};
    __syncthreads();

    const u16* bp1 = w1s + nt * 512 + lane * 8;
    const u16* bp2 = w2s + nt * 512 + lane * 8;

    ushort4 xlo[4], xhi[4];
#define LOAD_X(ch, t)                                                          \
    {                                                                          \
        int row = r2 * 128 + (ch) * 64 + rrf;                                  \
        int tok = tokens[row * 80 + (t)];                                      \
        const u16* xb = embp + tok * 100 + q * 8;                              \
        _Pragma("unroll")                                                      \
        for (int k2 = 0; k2 < 4; ++k2) {                                       \
            xlo[k2] = *(const ushort4*)(xb + k2 * 32);                         \
            xhi[k2] = *(const ushort4*)(xb + k2 * 32 + 4);                     \
        }                                                                      \
    }
#define XFRAG(k2) ({ union { ushort4 a[2]; bf16x8 v; } xu;                     \
                     xu.a[0] = xlo[k2]; xu.a[1] = xhi[k2]; xu.v; })

// in-wave gate transpose + LSTM cell: lane gathers the 4 gate pre-activations
// of its (unit,row) via 3 shfl_xor within the 4-lane gate nibble.
#define GATES(accv, B0, B1, B2, B3, cref, hout)                                \
    {                                                                          \
        float v0 = vext(accv, b);                                              \
        float v1 = __shfl_xor(vext(accv, b ^ 1), 1, 64);                       \
        float v2 = __shfl_xor(vext(accv, b ^ 2), 2, 64);                       \
        float v3 = __shfl_xor(vext(accv, b ^ 3), 3, 64);                       \
        float zf = sel4(v0, v1, v2, v3, b);                                    \
        float zi = sel4(v0, v1, v2, v3, b ^ 1);                                \
        float zc = sel4(v0, v1, v2, v3, b ^ 2);                                \
        float zo = sel4(v0, v1, v2, v3, b ^ 3);                                \
        float gf = fast_sigmoid(zf + B0);                                      \
        float gi = fast_sigmoid(zi + B1);                                      \
        float gc = fast_tanh(zc + B2);                                         \
        float go = fast_sigmoid(zo + B3);                                      \
        float cn = gf * cref + gi * gc;                                        \
        cref = cn;                                                             \
        hout = f2bf(go * fast_tanh(cn));                                       \
    }

    // ---- prologue per chain: z1(0) = x(0)-part only; gates1 -> h1(0) ----
#pragma unroll 1
    for (int ch = 0; ch < 2; ++ch) {
        LOAD_X(ch, 0);
        f32x4 acc = (f32x4){0.f, 0.f, 0.f, 0.f};
#pragma unroll
        for (int k2 = 0; k2 < 4; ++k2)
            acc = __builtin_amdgcn_mfma_f32_16x16x32_bf16(
                XFRAG(k2), as_bf16x8(*(const uint4*)(bp1 + (8 + k2) * 2048)), acc, 0, 0, 0);
        u16 h1o;
        GATES(acc, b1f, b1i, b1c, b1o, c1s[ch], h1o);
        h1g[((0 * 2 + ch) * 8 + r2) * CSLAB + hidx] = h1o;       // h1(0) parity 0
        ++ph[ch];
        rg_arrive(fgrp[ch], g, ph[ch], tid);
    }

    // ---- main loop: iteration i = z2(i) + z1(i+1), chains interleaved ----
#pragma unroll 1
    for (int i = 0; i < 79; ++i) {
        const int p_h2r = (i + 1) & 1, p_h1r = i & 1;
        const int p_h2w = i & 1, p_h1w = (i + 1) & 1;
#pragma unroll 1
        for (int ch = 0; ch < 2; ++ch) {
            LOAD_X(ch, i + 1);                    // issued before wait (hides under poll)
            rg_wait(fgrp[ch], ph[ch], tid);       // h2(i-1), h1(i) published

            const u16* h2b = h2g + ((p_h2r * 2 + ch) * 8 + r2) * CSLAB + loff;
            const u16* h1b = h1g + ((p_h1r * 2 + ch) * 8 + r2) * CSLAB + loff;
            u32x4 ag[16];
#pragma unroll
            for (int ks = 0; ks < 8; ++ks) ag[ks] = load_b128_sc0(h2b + ks * 2048);
#pragma unroll
            for (int ks = 0; ks < 8; ++ks) ag[8 + ks] = load_b128_sc0(h1b + ks * 2048);
            wait_vm0_fence_sched();

            f32x4 acc2 = (f32x4){0.f, 0.f, 0.f, 0.f};
#pragma unroll
            for (int ks = 0; ks < 16; ++ks)
                acc2 = __builtin_amdgcn_mfma_f32_16x16x32_bf16(
                    as_bf16x8v(ag[ks]), as_bf16x8(*(const uint4*)(bp2 + ks * 2048)), acc2, 0, 0, 0);
            f32x4 acc1 = (f32x4){0.f, 0.f, 0.f, 0.f};
#pragma unroll
            for (int ks = 0; ks < 8; ++ks)
                acc1 = __builtin_amdgcn_mfma_f32_16x16x32_bf16(
                    as_bf16x8v(ag[8 + ks]), as_bf16x8(*(const uint4*)(bp1 + ks * 2048)), acc1, 0, 0, 0);
#pragma unroll
            for (int k2 = 0; k2 < 4; ++k2)
                acc1 = __builtin_amdgcn_mfma_f32_16x16x32_bf16(
                    XFRAG(k2), as_bf16x8(*(const uint4*)(bp1 + (8 + k2) * 2048)), acc1, 0, 0, 0);

            u16 h2o, h1o;
            GATES(acc2, b2f, b2i, b2c, b2o, c2s[ch], h2o);
            GATES(acc1, b1f, b1i, b1c, b1o, c1s[ch], h1o);
            h2g[((p_h2w * 2 + ch) * 8 + r2) * CSLAB + hidx] = h2o;
            h1g[((p_h1w * 2 + ch) * 8 + r2) * CSLAB + hidx] = h1o;

            ++ph[ch];
            rg_arrive(fgrp[ch], g, ph[ch], tid);  // publish h2(i), h1(i+1)
        }
    }

    // ---- epilogue per chain: z2(79), gates2(79) ----
#pragma unroll 1
    for (int ch = 0; ch < 2; ++ch) {
        rg_wait(fgrp[ch], ph[ch], tid);           // h2(78) par0, h1(79) par1
        const u16* h2b = h2g + ((0 * 2 + ch) * 8 + r2) * CSLAB + loff;
        const u16* h1b = h1g + ((1 * 2 + ch) * 8 + r2) * CSLAB + loff;
        u32x4 ag[16];
#pragma unroll
        for (int ks = 0; ks < 8; ++ks) ag[ks] = load_b128_sc0(h2b + ks * 2048);
#pragma unroll
        for (int ks = 0; ks < 8; ++ks) ag[8 + ks] = load_b128_sc0(h1b + ks * 2048);
        wait_vm0_fence_sched();
        f32x4 acc2 = (f32x4){0.f, 0.f, 0.f, 0.f};
#pragma unroll
        for (int ks = 0; ks < 16; ++ks)
            acc2 = __builtin_amdgcn_mfma_f32_16x16x32_bf16(
                as_bf16x8v(ag[ks]), as_bf16x8(*(const uint4*)(bp2 + ks * 2048)), acc2, 0, 0, 0);
        u16 h2o;
        GATES(acc2, b2f, b2i, b2c, b2o, c2s[ch], h2o);
        h2g[((1 * 2 + ch) * 8 + r2) * CSLAB + hidx] = h2o;       // h2(79) parity 1
        ++ph[ch];
        rg_arrive(fgrp[ch], g, ph[ch], tid);
    }
    rg_wait(fgrp[0], ph[0], tid);
    rg_wait(fgrp[1], ph[1], tid);

    // ---- output: sigmoid(h2 @ w_out + b_out) by g==0 blocks ----
    if (g == 0) {
#pragma unroll 1
        for (int ch = 0; ch < 2; ++ch) {
            const u16* base = h2g + ((1 * 2 + ch) * 8 + r2) * CSLAB;
            int rr = tid >> 4, s = tid & 15;
            const u16* hp = base + s * 1024 + rr * 16;
            u32x4 hv0 = load_b128_sc0(hp);
            u32x4 hv1 = load_b128_sc0(hp + 8);
            wait_vm0_fence_sched();
            const u16* wq = wob + s * 16;
            union { u32x4 v[2]; u16 h[16]; } hu; hu.v[0] = hv0; hu.v[1] = hv1;
            float dot = 0.f;
#pragma unroll
            for (int k = 0; k < 16; ++k) dot += bf2f(hu.h[k]) * bf2f(wq[k]);
            __syncthreads();
            outscr[rr * 16 + s] = dot;
            __syncthreads();
            if (tid < 64) {
                float ssum = 0.f;
                for (int k = 0; k < 16; ++k) ssum += outscr[tid * 16 + k];
                out[r2 * 128 + ch * 64 + tid] = fast_sigmoid(ssum + bf2f(bob[0]));
            }
        }
    }
}

extern "C" void kernel_launch(void* const* d_in, const int* in_sizes, int n_in,
                              void* d_out, int out_size, void* d_ws, size_t ws_size,
                              hipStream_t stream) {
    const int* tokens = (const int*)d_in[0];
    const void* emb = d_in[1];
    const void* wf1 = d_in[2];  const void* bf1_ = d_in[3];
    const void* wi1 = d_in[4];  const void* bi1_ = d_in[5];
    const void* wc1 = d_in[6];  const void* bc1_ = d_in[7];
    const void* wo1 = d_in[8];  const void* bo1_ = d_in[9];
    const void* wf2 = d_in[10]; const void* bf2_ = d_in[11];
    const void* wi2 = d_in[12]; const void* bi2_ = d_in[13];
    const void* wc2 = d_in[14]; const void* bc2_ = d_in[15];
    const void* wo2 = d_in[16]; const void* bo2_ = d_in[17];
    const void* w_out = d_in[18];
    const void* b_out = d_in[19];

    u16* wp1 = (u16*)d_ws;                 // 393216
    u16* wp2 = wp1 + 16 * 12 * 4 * 512;    // 524288
    u16* b1p = wp2 + 16 * 16 * 4 * 512;    // 1024
    u16* b2p = b1p + 1024;                 // 1024
    u16* wob = b2p + 1024;                 // 256
    u16* bob = wob + 256;                  // 8 (pad)
    u16* embp = bob + 8;                   // 1,000,000 (16B-aligned)
    u16* h1g = embp + 1000000;             // 2par x 2ch x 8 x 16384 = 524288
    u16* h2g = h1g + 524288;               // same
    uint* flags = (uint*)(h2g + 524288);   // 2ch x 8 x 64 uints

    pack_w<<<dim3(16 * 12), dim3(256), 0, stream>>>(wf1, wi1, wc1, wo1, bf1_, bi1_, bc1_, bo1_,
                                                    wp1, b1p, 356, 12);
    pack_w<<<dim3(16 * 16), dim3(256), 0, stream>>>(wf2, wi2, wc2, wo2, bf2_, bi2_, bc2_, bo2_,
                                                    wp2, b2p, 512, 16);
    pack_misc<<<dim3(512), dim3(256), 0, stream>>>(emb, w_out, b_out, embp, wob, bob, (uint*)h1g);
    lstm_kernel<<<dim3(128), dim3(1024), 0, stream>>>(tokens, embp, wp1, b1p, wp2, b2p,
                                                      wob, bob, h1g, h2g, flags, (float*)d_out);
}